// Round 6
// baseline (843.734 us; speedup 1.0000x reference)
//
#include <hip/hip_runtime.h>
#include <math.h>

#define BLK   256
#define IPT   16
#define TILE  4096
#define CHUNK 1024             // per-wave contiguous chunk inside a tile
#define BINS  256

#define FLAG_AGG (1u << 30)
#define FLAG_PRE (2u << 30)
#define VALMASK  0x3FFFFFFFu

// ---------------- workspace zeroing (graph-safe) ----------------
__global__ __launch_bounds__(256) void k_zero(unsigned* __restrict__ p, int n)
{
    int i = blockIdx.x * 256 + threadIdx.x;
    int T = gridDim.x * 256;
    for (; i < n; i += T) p[i] = 0;
}

// ---------------- per-point math + key gen, input order -> 16-float rows ----------------
__global__ __launch_bounds__(256) void k_rows(const float* __restrict__ pts,
                                              const float* __restrict__ cols,
                                              const float* __restrict__ opa,
                                              const float* __restrict__ scl,
                                              const float* __restrict__ qt,
                                              const float* __restrict__ w2v,
                                              const float* __restrict__ fpm,
                                              const float* __restrict__ tanx_p,
                                              const float* __restrict__ tany_p,
                                              const float* __restrict__ fx_p,
                                              const float* __restrict__ fy_p,
                                              const int* __restrict__ wp,
                                              const int* __restrict__ hp,
                                              float* __restrict__ rows,
                                              unsigned* __restrict__ keys,
                                              int N)
{
    int i = blockIdx.x * 256 + threadIdx.x;
    if (i >= N) return;

    float x = pts[3*i+0], y = pts[3*i+1], z = pts[3*i+2];

    // depth key: zv = x*0 + y*0 + z*1 + 5 -> fl(z+5) exactly, matches numpy bitwise
    float zv = x*w2v[2] + y*w2v[6] + z*w2v[10] + w2v[14];
    bool in_view = (zv >= 0.2f);
    {
        float key = in_view ? zv : __int_as_float(0x7f800000);
        unsigned u = __float_as_uint(key);
        u ^= (u & 0x80000000u) ? 0xFFFFFFFFu : 0x80000000u;   // float -> sortable u32
        keys[i] = u;
    }

    float4 q4 = *(const float4*)(qt + 4*i);
    float qw = q4.x, qx = q4.y, qy = q4.z, qz = q4.w;
    float rn = __builtin_amdgcn_rsqf(qw*qw + qx*qx + qy*qy + qz*qz);
    qw *= rn; qx *= rn; qy *= rn; qz *= rn;
    float R00 = 1.f - 2.f*(qy*qy + qz*qz), R01 = 2.f*(qx*qy - qw*qz), R02 = 2.f*(qx*qz + qw*qy);
    float R10 = 2.f*(qx*qy + qw*qz), R11 = 1.f - 2.f*(qx*qx + qz*qz), R12 = 2.f*(qy*qz - qw*qx);
    float R20 = 2.f*(qx*qz - qw*qy), R21 = 2.f*(qy*qz + qw*qx), R22 = 1.f - 2.f*(qx*qx + qy*qy);

    float s0 = scl[3*i+0], s1 = scl[3*i+1], s2 = scl[3*i+2];
    float M00=R00*s0, M01=R01*s1, M02=R02*s2;
    float M10=R10*s0, M11=R11*s1, M12=R12*s2;
    float M20=R20*s0, M21=R21*s1, M22=R22*s2;
    float C00=M00*M00+M01*M01+M02*M02;
    float C01=M00*M10+M01*M11+M02*M12;
    float C02=M00*M20+M01*M21+M02*M22;
    float C11=M10*M10+M11*M11+M12*M12;
    float C12=M10*M20+M11*M21+M12*M22;
    float C22=M20*M20+M21*M21+M22*M22;

    float pvx = x*w2v[0] + y*w2v[4] + z*w2v[8]  + w2v[12];
    float pvy = x*w2v[1] + y*w2v[5] + z*w2v[9]  + w2v[13];

    float cx = x*fpm[0] + y*fpm[4] + z*fpm[8]  + fpm[12];
    float cy = x*fpm[1] + y*fpm[5] + z*fpm[9]  + fpm[13];
    float cw = x*fpm[3] + y*fpm[7] + z*fpm[11] + fpm[15];
    float rcw = __builtin_amdgcn_rcpf(cw);
    float Wf = (float)wp[0], Hf = (float)hp[0];
    float px = ((cx*rcw + 1.f) * Wf - 1.f) * 0.5f;
    float py = ((cy*rcw + 1.f) * Hf - 1.f) * 0.5f;

    float tanX = tanx_p[0], tanY = tany_p[0], fx = fx_p[0], fy = fy_p[0];
    float lx = 1.3f * tanX, ly = 1.3f * tanY;
    float rzv = __builtin_amdgcn_rcpf(zv);
    float xc = fminf(fmaxf(pvx*rzv, -lx), lx) * zv;
    float yc = fminf(fmaxf(pvy*rzv, -ly), ly) * zv;
    float rz2 = rzv * rzv;
    float J00 = fx * rzv, J02 = -(fx * xc) * rz2;
    float J11 = fy * rzv, J12 = -(fy * yc) * rz2;

    float T00 = J00*w2v[0] + J02*w2v[2];
    float T01 = J00*w2v[4] + J02*w2v[6];
    float T02 = J00*w2v[8] + J02*w2v[10];
    float T10 = J11*w2v[1] + J12*w2v[2];
    float T11 = J11*w2v[5] + J12*w2v[6];
    float T12 = J11*w2v[9] + J12*w2v[10];

    float V00 = T00*C00 + T01*C01 + T02*C02;
    float V01 = T00*C01 + T01*C11 + T02*C12;
    float V02 = T00*C02 + T01*C12 + T02*C22;
    float V10 = T10*C00 + T11*C01 + T12*C02;
    float V11 = T10*C01 + T11*C11 + T12*C12;
    float V12 = T10*C02 + T11*C12 + T12*C22;
    float c00 = V00*T00 + V01*T01 + V02*T02;
    float c01 = V00*T10 + V01*T11 + V02*T12;
    float c10 = V10*T00 + V11*T01 + V12*T02;
    float c11 = V10*T10 + V11*T11 + V12*T12;

    float det = c00*c11 - c01*c10;
    float det_safe = (fabsf(det) < 1e-6f) ? 1e-6f : det;
    float rdet = __builtin_amdgcn_rcpf(det_safe);
    float i00 =  c11 * rdet, i01 = -c01 * rdet, i11 = c00 * rdet;
    float mid = 0.5f * (c00 + c11);
    float inter = fmaxf(mid*mid - det, 0.1f);
    float lam = mid + sqrtf(inter);
    float radius = ceilf(3.0f * sqrtf(fmaxf(lam, 0.0f)));
    float op = __builtin_amdgcn_rcpf(1.0f + __expf(-opa[i]));

    float cr = cols[3*i+0], cg = cols[3*i+1], cb = cols[3*i+2];

    float4* rp = (float4*)(rows + (size_t)i * 16);
    rp[0] = make_float4(px,  py,  zv,  c00);
    rp[1] = make_float4(c01, c11, i00, i01);
    rp[2] = make_float4(i11, radius, cr, cg);
    rp[3] = make_float4(cb,  op,  in_view ? 1.0f : 0.0f, 0.f);
}

// ---------------- one-shot histograms for ALL 4 digit positions ----------------
// (digit histograms are permutation-invariant -> compute once from original keys)
__global__ __launch_bounds__(256) void k_hist_all(const unsigned* __restrict__ keys,
                                                  int N, unsigned* __restrict__ gh)
{
    __shared__ unsigned hb[4][BINS];   // 4 KB
    int t = threadIdx.x, l = t & 63;
    hb[0][t] = 0; hb[1][t] = 0; hb[2][t] = 0; hb[3][t] = 0;
    __syncthreads();

    int gtid = blockIdx.x * 256 + t;
    int T = gridDim.x * 256;
    int M4 = N >> 2;
    for (int i = gtid; i < M4; i += T) {
        uint4 v = ((const uint4*)keys)[i];
        unsigned ks[4] = {v.x, v.y, v.z, v.w};
        #pragma unroll
        for (int c = 0; c < 4; ++c) {
            unsigned kk = ks[c];
            #pragma unroll
            for (int p = 0; p < 4; ++p) {
                unsigned d = (kk >> (8*p)) & 255u;
                // wave-aggregate same-digit counts to kill same-address atomic chains
                unsigned long long mm = __ballot(true);
                #pragma unroll
                for (int bb = 0; bb < 8; ++bb) {
                    unsigned long long bal = __ballot(((d >> bb) & 1u) != 0u);
                    mm &= ((d >> bb) & 1u) ? bal : ~bal;
                }
                unsigned long long below = mm & ((1ull << l) - 1ull);
                if (below == 0ull)
                    atomicAdd(&hb[p][d], (unsigned)__popcll(mm));
            }
        }
    }
    if (gtid == 0) {
        for (int i = M4 << 2; i < N; ++i) {
            unsigned kk = keys[i];
            for (int p = 0; p < 4; ++p) atomicAdd(&hb[p][(kk >> (8*p)) & 255u], 1u);
        }
    }
    __syncthreads();
    #pragma unroll
    for (int p = 0; p < 4; ++p)
        if (hb[p][t]) atomicAdd(&gh[p * BINS + t], hb[p][t]);
}

// ---------------- exclusive scan of the 4x256 global histograms (in place) ----------------
__global__ __launch_bounds__(256) void k_scan_all(unsigned* __restrict__ gh)
{
    __shared__ unsigned tsum[BINS];
    int t = threadIdx.x;
    for (int p = 0; p < 4; ++p) {
        tsum[t] = gh[p * BINS + t];
        __syncthreads();
        for (int off = 1; off < 256; off <<= 1) {
            unsigned u = (t >= off) ? tsum[t - off] : 0u;
            __syncthreads();
            tsum[t] += u;
            __syncthreads();
        }
        unsigned excl = (t == 0) ? 0u : tsum[t - 1];
        __syncthreads();
        gh[p * BINS + t] = excl;
        __syncthreads();
    }
}

// ---------------- stable 8-bit scatter with decoupled lookback ----------------
// Tile order via atomic ticket (arrival order == tile order -> no deadlock).
// Tile-internal ranking identical to the verified round-4 kernel.
__global__ __launch_bounds__(256) void k_scatter_lb(const unsigned* __restrict__ keys,
                                                    const unsigned* __restrict__ vals, // null => identity
                                                    int N, int shift,
                                                    const unsigned* __restrict__ gbase, // 256 excl digit bases
                                                    unsigned* __restrict__ tstate,      // numTiles*BINS
                                                    unsigned* __restrict__ ticket,
                                                    unsigned* __restrict__ okeys,       // null => skip
                                                    unsigned* __restrict__ ovals)
{
    __shared__ unsigned short wcnt[4][BINS];   // 2 KB
    __shared__ unsigned digStartL[BINS];
    __shared__ unsigned tileBase[BINS];
    __shared__ unsigned tscan[BINS];
    __shared__ unsigned stage[TILE];           // 16 KB
    __shared__ unsigned vt_s;

    int t = threadIdx.x;
    if (t == 0) vt_s = atomicAdd(ticket, 1u);
    ((unsigned*)wcnt)[t] = 0; ((unsigned*)wcnt)[256 + t] = 0;
    __syncthreads();

    int b = (int)vt_s;
    int w = t >> 6, l = t & 63;
    int base = b * TILE;
    int nvalid = N - base; if (nvalid < 0) nvalid = 0; if (nvalid > TILE) nvalid = TILE;
    int wbase = base + w * CHUNK;

    unsigned k_[IPT];
    unsigned short rw_[IPT];
    unsigned char d_[IPT];

    #pragma unroll
    for (int it = 0; it < IPT; ++it) {
        int e = wbase + it * 64 + l;
        bool ok = e < N;
        unsigned kk = ok ? keys[e] : 0u;
        unsigned d = (kk >> shift) & 255u;
        unsigned long long mm = __ballot(ok);
        #pragma unroll
        for (int bb = 0; bb < 8; ++bb) {
            unsigned long long bal = __ballot(ok && ((d >> bb) & 1u));
            mm &= ((d >> bb) & 1u) ? bal : ~bal;
        }
        unsigned long long below = mm & ((1ull << l) - 1ull);
        unsigned rk = (unsigned)__popcll(below);
        unsigned before = (unsigned)wcnt[w][d];
        if (ok && rk == 0)
            wcnt[w][d] = (unsigned short)(before + (unsigned)__popcll(mm));
        k_[it]  = kk;
        rw_[it] = (unsigned short)(before + rk);
        d_[it]  = (unsigned char)d;
    }
    __syncthreads();

    // cross-wave prefix per digit + publish tile aggregate
    unsigned own;
    {
        unsigned c0 = wcnt[0][t], c1 = wcnt[1][t], c2 = wcnt[2][t], c3 = wcnt[3][t];
        wcnt[0][t] = 0;
        wcnt[1][t] = (unsigned short)c0;
        wcnt[2][t] = (unsigned short)(c0 + c1);
        wcnt[3][t] = (unsigned short)(c0 + c1 + c2);
        own = c0 + c1 + c2 + c3;
        tscan[t] = own;
        __hip_atomic_store(&tstate[(size_t)b * BINS + t], FLAG_AGG | own,
                           __ATOMIC_RELEASE, __HIP_MEMORY_SCOPE_AGENT);
    }
    __syncthreads();
    for (int off = 1; off < 256; off <<= 1) {
        unsigned u = (t >= off) ? tscan[t - off] : 0u;
        __syncthreads();
        tscan[t] += u;
        __syncthreads();
    }
    digStartL[t] = (t == 0) ? 0u : tscan[t - 1];

    // decoupled lookback: thread t owns digit t
    {
        unsigned sum = 0;
        int p = b - 1;
        while (p >= 0) {
            unsigned s;
            do {
                s = __hip_atomic_load(&tstate[(size_t)p * BINS + t],
                                      __ATOMIC_RELAXED, __HIP_MEMORY_SCOPE_AGENT);
                if ((s >> 30) == 0u) __builtin_amdgcn_s_sleep(1);
            } while ((s >> 30) == 0u);
            sum += s & VALMASK;
            if (s & FLAG_PRE) break;
            --p;
        }
        tileBase[t] = gbase[t] + sum;
        __hip_atomic_store(&tstate[(size_t)b * BINS + t], FLAG_PRE | (sum + own),
                           __ATOMIC_RELEASE, __HIP_MEMORY_SCOPE_AGENT);
    }
    __syncthreads();

    // local positions; stage keys
    unsigned lp_[IPT];
    #pragma unroll
    for (int it = 0; it < IPT; ++it) {
        int e = wbase + it * 64 + l;
        if (e < N) {
            unsigned d = d_[it];
            lp_[it] = digStartL[d] + (unsigned)wcnt[w][d] + (unsigned)rw_[it];
            stage[lp_[it]] = k_[it];
        }
    }
    __syncthreads();

    unsigned pos_[IPT];
    #pragma unroll
    for (int it = 0; it < IPT; ++it) {
        int p = it * BLK + t;
        if (p < nvalid) {
            unsigned kk = stage[p];
            unsigned d = (kk >> shift) & 255u;
            unsigned pos = tileBase[d] + ((unsigned)p - digStartL[d]);
            pos_[it] = pos;
            if (okeys) okeys[pos] = kk;
        }
    }
    __syncthreads();

    #pragma unroll
    for (int it = 0; it < IPT; ++it) {
        int e = wbase + it * 64 + l;
        if (e < N) stage[lp_[it]] = vals ? vals[e] : (unsigned)e;
    }
    __syncthreads();
    #pragma unroll
    for (int it = 0; it < IPT; ++it) {
        int p = it * BLK + t;
        if (p < nvalid) ovals[pos_[it]] = stage[p];
    }
}

// ---------------- permute 64B rows -> compact 21-float sorted output ----------------
__global__ __launch_bounds__(256) void k_perm(const unsigned* __restrict__ order,
                                              const float* __restrict__ rows,
                                              float* __restrict__ out, int N)
{
    __shared__ float srow[256 * 21];
    int i = blockIdx.x * 256 + threadIdx.x;
    if (i < N) {
        int j = (int)order[i];
        const float4* rp = (const float4*)(rows + (size_t)j * 16);
        float4 a = rp[0], b4 = rp[1], c4 = rp[2], d4 = rp[3];
        float px = a.x,  py = a.y,  zv = a.z,  c00 = a.w;
        float c01 = b4.x, c11 = b4.y, i00 = b4.z, i01 = b4.w;
        float i11 = c4.x, rad = c4.y, cr = c4.z, cg = c4.w;
        float cb = d4.x,  op = d4.y,  iv = d4.z;
        float* r = &srow[threadIdx.x * 21];
        r[0]=px; r[1]=py; r[2]=zv;
        r[3]=c00; r[4]=c01; r[5]=c01; r[6]=c11;        // c10 == c01 (symmetric, ~ulp)
        r[7]=i00; r[8]=i01; r[9]=i01; r[10]=i11;       // i10 == i01
        r[11]=rad;
        r[12]=floorf(px - rad); r[13]=floorf(py - rad);
        r[14]=ceilf(px + rad);  r[15]=ceilf(py + rad);
        r[16]=cr; r[17]=cg; r[18]=cb;
        r[19]=op; r[20]=iv;
    }
    __syncthreads();
    int blockBase = blockIdx.x * 256;
    int valid = N - blockBase; if (valid > 256) valid = 256;
    if (valid > 0) {
        float* dst = out + (size_t)blockBase * 21;
        for (int u = threadIdx.x; u < valid * 21; u += 256) dst[u] = srow[u];
    }
}

extern "C" void kernel_launch(void* const* d_in, const int* in_sizes, int n_in,
                              void* d_out, int out_size, void* d_ws, size_t ws_size,
                              hipStream_t stream)
{
    const float* pts  = (const float*)d_in[0];
    const float* cols = (const float*)d_in[1];
    const float* opa  = (const float*)d_in[2];
    const float* scl  = (const float*)d_in[3];
    const float* qt   = (const float*)d_in[4];
    const float* w2v  = (const float*)d_in[5];
    const float* fpm  = (const float*)d_in[6];
    const float* tanx = (const float*)d_in[7];
    const float* tany = (const float*)d_in[8];
    const float* fx   = (const float*)d_in[9];
    const float* fy   = (const float*)d_in[10];
    const int*   wp   = (const int*)d_in[11];
    const int*   hp   = (const int*)d_in[12];

    int N = in_sizes[0] / 3;
    int numTiles = (N + TILE - 1) / TILE;
    int nb = (N + 255) / 256;

    unsigned* kA     = (unsigned*)d_ws;
    unsigned* kB     = kA + N;
    unsigned* vA     = kB + N;
    unsigned* vB     = vA + N;
    unsigned* gh     = vB + N;                          // 4*256
    unsigned* tick   = gh + 4 * BINS;                   // 4
    unsigned* tstate = tick + 4;                        // 4 * numTiles * BINS
    float*    rows   = (float*)(tstate + (size_t)4 * numTiles * BINS);

    int zwords = 4 * BINS + 4 + 4 * numTiles * BINS;
    int zb = (zwords + 255) / 256; if (zb > 1024) zb = 1024;

    k_zero<<<zb, 256, 0, stream>>>(gh, zwords);
    k_rows<<<nb, 256, 0, stream>>>(pts, cols, opa, scl, qt, w2v, fpm,
                                   tanx, tany, fx, fy, wp, hp, rows, kA, N);
    k_hist_all<<<512, 256, 0, stream>>>(kA, N, gh);
    k_scan_all<<<1, 256, 0, stream>>>(gh);

    // pass 0: kA (identity vals) -> kB, vA
    k_scatter_lb<<<numTiles, 256, 0, stream>>>(kA, nullptr, N, 0,  gh + 0*BINS,
                                               tstate + (size_t)0*numTiles*BINS, tick + 0, kB, vA);
    // pass 1: kB, vA -> kA, vB
    k_scatter_lb<<<numTiles, 256, 0, stream>>>(kB, vA, N, 8,  gh + 1*BINS,
                                               tstate + (size_t)1*numTiles*BINS, tick + 1, kA, vB);
    // pass 2: kA, vB -> kB, vA
    k_scatter_lb<<<numTiles, 256, 0, stream>>>(kA, vB, N, 16, gh + 2*BINS,
                                               tstate + (size_t)2*numTiles*BINS, tick + 2, kB, vA);
    // pass 3: kB, vA -> vB only
    k_scatter_lb<<<numTiles, 256, 0, stream>>>(kB, vA, N, 24, gh + 3*BINS,
                                               tstate + (size_t)3*numTiles*BINS, tick + 3, nullptr, vB);

    k_perm<<<nb, 256, 0, stream>>>(vB, rows, (float*)d_out, N);
}